// Round 3
// baseline (916.980 us; speedup 1.0000x reference)
//
#include <hip/hip_runtime.h>
#include <math.h>

// LCGLoss: B=256, L=512, D=512.
// S[(b,l),k] = (text @ C^T)[(b,l),k],  Cb[k][d] = bf16( (ip @ W_ML)[k][d] / tau )
// loss = mean over valid (i,l) of 0.5*(denom_log + logaddexp(s_iji, cross_log[i])) - s_iji

#define B_ 256
#define L_ 512
#define D_ 512
#define ROWS (B_ * L_)      // 131072
#define NT (ROWS / 64)      // 2048 row-tiles
#define NEG_INF (-INFINITY)

typedef __attribute__((ext_vector_type(8))) short s8_t;     // 8 bf16 in 4 VGPRs
typedef __attribute__((ext_vector_type(4))) float f4_t;

__device__ inline unsigned short f2bf(float x) {
    unsigned int u = __float_as_uint(x);
    u += 0x7FFFu + ((u >> 16) & 1u);          // round-to-nearest-even
    return (unsigned short)(u >> 16);
}

// ---------------- K0: ip[k][e] = sum_d img[k][d] * Wmv[e][d]  (64x64 tiles, 32 blocks) ----
__global__ __launch_bounds__(256) void ip_kernel(const float* __restrict__ img,
                                                 const float* __restrict__ Wmv,
                                                 float* __restrict__ ip) {
    int kt = blockIdx.x >> 3, et = blockIdx.x & 7;
    __shared__ float As[64][36];
    __shared__ float Bs[64][36];
    int tid = threadIdx.x;
    int lr = tid >> 2, lc = (tid & 3) * 8;
    int ty = tid >> 4, tx = tid & 15;
    float acc[4][4] = {};
    for (int d0 = 0; d0 < D_; d0 += 32) {
        f4_t a0 = *(const f4_t*)(img + (size_t)(kt * 64 + lr) * D_ + d0 + lc);
        f4_t a1 = *(const f4_t*)(img + (size_t)(kt * 64 + lr) * D_ + d0 + lc + 4);
        f4_t b0 = *(const f4_t*)(Wmv + (size_t)(et * 64 + lr) * D_ + d0 + lc);
        f4_t b1 = *(const f4_t*)(Wmv + (size_t)(et * 64 + lr) * D_ + d0 + lc + 4);
        __syncthreads();
        *(f4_t*)(&As[lr][lc]) = a0; *(f4_t*)(&As[lr][lc + 4]) = a1;
        *(f4_t*)(&Bs[lr][lc]) = b0; *(f4_t*)(&Bs[lr][lc + 4]) = b1;
        __syncthreads();
        for (int d = 0; d < 32; d++) {
            float av[4], bv[4];
#pragma unroll
            for (int i = 0; i < 4; i++) { av[i] = As[ty * 4 + i][d]; bv[i] = Bs[tx * 4 + i][d]; }
#pragma unroll
            for (int i = 0; i < 4; i++)
#pragma unroll
                for (int j = 0; j < 4; j++) acc[i][j] = fmaf(av[i], bv[j], acc[i][j]);
        }
    }
#pragma unroll
    for (int i = 0; i < 4; i++)
#pragma unroll
        for (int j = 0; j < 4; j++)
            ip[(size_t)(kt * 64 + ty * 4 + i) * D_ + et * 64 + tx * 4 + j] = acc[i][j];
}

// ---------------- K1: Cb[k][d] = bf16( sum_e ip[k][e]*Wml[e][d] / tau ) ----------------
__global__ __launch_bounds__(256) void c_kernel(const float* __restrict__ ip,
                                                const float* __restrict__ Wml,
                                                const float* __restrict__ tau,
                                                unsigned short* __restrict__ Cb) {
    int kt = blockIdx.x >> 3, dt = blockIdx.x & 7;
    __shared__ float As[64][36];
    __shared__ float Bs[32][68];
    int tid = threadIdx.x;
    int lr = tid >> 2, lc = (tid & 3) * 8;
    int ber = tid >> 3, bec = (tid & 7) * 8;
    int ty = tid >> 4, tx = tid & 15;
    float acc[4][4] = {};
    for (int e0 = 0; e0 < D_; e0 += 32) {
        f4_t a0 = *(const f4_t*)(ip + (size_t)(kt * 64 + lr) * D_ + e0 + lc);
        f4_t a1 = *(const f4_t*)(ip + (size_t)(kt * 64 + lr) * D_ + e0 + lc + 4);
        f4_t b0 = *(const f4_t*)(Wml + (size_t)(e0 + ber) * D_ + dt * 64 + bec);
        f4_t b1 = *(const f4_t*)(Wml + (size_t)(e0 + ber) * D_ + dt * 64 + bec + 4);
        __syncthreads();
        *(f4_t*)(&As[lr][lc]) = a0; *(f4_t*)(&As[lr][lc + 4]) = a1;
        *(f4_t*)(&Bs[ber][bec]) = b0; *(f4_t*)(&Bs[ber][bec + 4]) = b1;
        __syncthreads();
        for (int e = 0; e < 32; e++) {
            float av[4], bv[4];
#pragma unroll
            for (int i = 0; i < 4; i++) { av[i] = As[ty * 4 + i][e]; bv[i] = Bs[e][tx * 4 + i]; }
#pragma unroll
            for (int i = 0; i < 4; i++)
#pragma unroll
                for (int j = 0; j < 4; j++) acc[i][j] = fmaf(av[i], bv[j], acc[i][j]);
        }
    }
    float it = 1.0f / fmaxf(tau[0], 0.001f);
#pragma unroll
    for (int i = 0; i < 4; i++)
#pragma unroll
        for (int j = 0; j < 4; j++)
            Cb[(size_t)(kt * 64 + ty * 4 + i) * D_ + dt * 64 + tx * 4 + j] = f2bf(acc[i][j] * it);
}

// ---------------- Kmask: mbits[l*4+w] bit j = valid[w*64+j, l] ----------------
__global__ __launch_bounds__(256) void mask_kernel(const int* __restrict__ pad,
                                                   unsigned long long* __restrict__ mbits) {
    int l = blockIdx.x;
    int w = threadIdx.x >> 6;
    int j = threadIdx.x & 63;
    unsigned long long bal = __ballot(pad[(w * 64 + j) * L_ + l] == 0);
    if (j == 0) mbits[l * 4 + w] = bal;
}

// ---------------- K2: bf16 MFMA GEMM (64 rows x 256 cols per block) + fused reductions ----
__global__ __launch_bounds__(256) void gemm_mfma_kernel(
    const float* __restrict__ text, const unsigned short* __restrict__ Cb,
    const unsigned long long* __restrict__ mbits,
    float* __restrict__ denom, float* __restrict__ siji,
    float* __restrict__ crossM, float* __restrict__ crossS) {
    // staging (phase 1): a_s 64x40 bf16 (1280 fl), b_s 256x40 bf16 (5120 fl)
    // epilogue (phase 2): Sh[32][257] + pm/ps[128] + rvf[32] = 8512 fl (34 KB)
    __shared__ __align__(16) float lds[8512];
    unsigned short* a_s = (unsigned short*)lds;
    unsigned short* b_s = (unsigned short*)(lds + 1280);
    float* Sh  = lds;
    float* pm  = lds + 8224;
    float* ps  = lds + 8352;
    float* rvf = lds + 8480;

    const int tile = blockIdx.x;
    const int row0 = tile * 64;
    const int bIdx = row0 >> 9;
    const int l0 = row0 & 511;
    const int tid = threadIdx.x;
    const int wave = tid >> 6;
    const int lane = tid & 63;
    const int qd = lane >> 4;     // quad 0..3
    const int mm = lane & 15;

    f4_t acc[4][4];
#pragma unroll
    for (int mt = 0; mt < 4; mt++)
#pragma unroll
        for (int nt = 0; nt < 4; nt++)
#pragma unroll
            for (int r = 0; r < 4; r++) acc[mt][nt][r] = 0.f;

    const int arow = tid >> 2, akq = tid & 3;
    const float* aptr = text + (size_t)(row0 + arow) * D_ + akq * 8;
    const int bkq = tid & 3, bn = tid >> 2;
    const unsigned short* bptr = Cb + (size_t)bn * D_ + bkq * 8;

#pragma unroll 1
    for (int k0 = 0; k0 < D_; k0 += 32) {
        f4_t av0 = *(const f4_t*)(aptr + k0);
        f4_t av1 = *(const f4_t*)(aptr + k0 + 4);
        s8_t bv[4];
#pragma unroll
        for (int i = 0; i < 4; i++)
            bv[i] = *(const s8_t*)(bptr + (size_t)i * 64 * D_ + k0);
        __syncthreads();
        s8_t a8;
        a8[0] = (short)f2bf(av0[0]); a8[1] = (short)f2bf(av0[1]);
        a8[2] = (short)f2bf(av0[2]); a8[3] = (short)f2bf(av0[3]);
        a8[4] = (short)f2bf(av1[0]); a8[5] = (short)f2bf(av1[1]);
        a8[6] = (short)f2bf(av1[2]); a8[7] = (short)f2bf(av1[3]);
        *(s8_t*)(a_s + arow * 40 + akq * 8) = a8;
#pragma unroll
        for (int i = 0; i < 4; i++)
            *(s8_t*)(b_s + (bn + i * 64) * 40 + bkq * 8) = bv[i];
        __syncthreads();
        s8_t af[4], bf[4];
#pragma unroll
        for (int mt = 0; mt < 4; mt++)
            af[mt] = *(const s8_t*)(a_s + (mt * 16 + mm) * 40 + qd * 8);
#pragma unroll
        for (int nt = 0; nt < 4; nt++)
            bf[nt] = *(const s8_t*)(b_s + (wave * 64 + nt * 16 + mm) * 40 + qd * 8);
#pragma unroll
        for (int mt = 0; mt < 4; mt++)
#pragma unroll
            for (int nt = 0; nt < 4; nt++)
                acc[mt][nt] = __builtin_amdgcn_mfma_f32_16x16x32_bf16(
                    af[mt], bf[nt], acc[mt][nt], 0, 0, 0);
    }

    // -------- epilogue: two 32-row halves through LDS --------
    float cm = NEG_INF, cs = 0.f;
    const int mw = bIdx >> 6, mb = bIdx & 63;

    for (int h = 0; h < 2; h++) {
        __syncthreads();                 // staging/frag reads (h=0) or prev-half reads done
        // write MFMA C-layout frags: row = mt*16 + qd*4 + r, col = wave*64 + nt*16 + mm
#pragma unroll
        for (int mt2 = 0; mt2 < 2; mt2++) {
            int mt = h * 2 + mt2;
            int rl = mt2 * 16 + qd * 4;  // row within this 32-row half
#pragma unroll
            for (int nt = 0; nt < 4; nt++) {
                int col = wave * 64 + nt * 16 + mm;
#pragma unroll
                for (int r = 0; r < 4; r++)
                    Sh[(rl + r) * 257 + col] = acc[mt][nt][r];
            }
        }
        if (tid < 32) {
            int l = l0 + h * 32 + tid;
            rvf[tid] = (float)((mbits[l * 4 + mw] >> mb) & 1ULL);  // valid[bIdx, l]
        }
        __syncthreads();

        // cross partial: column = tid, exclude column == bIdx; rows need valid[bIdx,l]
        if (tid != bIdx) {
            float m2 = NEG_INF;
            for (int r = 0; r < 32; r++)
                if (rvf[r] != 0.f) m2 = fmaxf(m2, Sh[r * 257 + tid]);
            if (m2 > NEG_INF) {
                float s2 = 0.f;
                for (int r = 0; r < 32; r++)
                    if (rvf[r] != 0.f) s2 += expf(Sh[r * 257 + tid] - m2);
                if (cm == NEG_INF) { cm = m2; cs = s2; }
                else {
                    float M = fmaxf(cm, m2);
                    cs = cs * expf(cm - M) + s2 * expf(m2 - M);
                    cm = M;
                }
            }
        }
        // denom partials: 128 threads, (row = tid&31, grp = tid>>5 covering 64 cols)
        if (tid < 128) {
            int row = tid & 31, grp = tid >> 5;
            int l = l0 + h * 32 + row;
            unsigned long long bits = mbits[l * 4 + grp];
            const float* Srow = Sh + row * 257 + grp * 64;
            float m = NEG_INF;
            for (int c = 0; c < 64; c++)
                if ((bits >> c) & 1ULL) m = fmaxf(m, Srow[c]);
            float s = 0.f;
            if (m > NEG_INF)
                for (int c = 0; c < 64; c++)
                    if ((bits >> c) & 1ULL) s += expf(Srow[c] - m);
            pm[grp * 32 + row] = m;
            ps[grp * 32 + row] = s;
        }
        __syncthreads();
        if (tid < 32) {
            float m0 = pm[tid], m1 = pm[32 + tid], m2 = pm[64 + tid], m3 = pm[96 + tid];
            float M = fmaxf(fmaxf(m0, m1), fmaxf(m2, m3));
            float dl;
            if (M == NEG_INF) dl = NEG_INF;
            else {
                float s = ps[tid] * expf(m0 - M) + ps[32 + tid] * expf(m1 - M) +
                          ps[64 + tid] * expf(m2 - M) + ps[96 + tid] * expf(m3 - M);
                dl = M + logf(s);
            }
            int gr = row0 + h * 32 + tid;
            denom[gr] = dl;
            siji[gr] = Sh[tid * 257 + bIdx];
        }
    }
    crossM[(size_t)tid * NT + tile] = cm;
    crossS[(size_t)tid * NT + tile] = cs;
}

// ---------------- K3: cross_log[i] = merge of 2048 (m,s) partials ----------------
__global__ __launch_bounds__(256) void cross_combine_kernel(const float* __restrict__ crossM,
                                                            const float* __restrict__ crossS,
                                                            float* __restrict__ crossLog) {
    int i = blockIdx.x;
    int tid = threadIdx.x;
    float m = NEG_INF, s = 0.f;
    for (int e = 0; e < NT / 256; e++) {
        int t = e * 256 + tid;
        float m2 = crossM[(size_t)i * NT + t];
        float s2 = crossS[(size_t)i * NT + t];
        if (m2 > NEG_INF) {
            if (m == NEG_INF) { m = m2; s = s2; }
            else {
                float M = fmaxf(m, m2);
                s = s * expf(m - M) + s2 * expf(m2 - M);
                m = M;
            }
        }
    }
    __shared__ float sm[256], ss[256];
    sm[tid] = m; ss[tid] = s;
    __syncthreads();
    for (int off = 128; off > 0; off >>= 1) {
        if (tid < off) {
            float m1 = sm[tid], s1 = ss[tid];
            float m2 = sm[tid + off], s2 = ss[tid + off];
            float M = fmaxf(m1, m2);
            float sv;
            if (M == NEG_INF) sv = 0.f;
            else sv = s1 * expf(m1 - M) + s2 * expf(m2 - M);
            sm[tid] = M; ss[tid] = sv;
        }
        __syncthreads();
    }
    if (tid == 0) crossLog[i] = (sm[0] == NEG_INF) ? NEG_INF : sm[0] + logf(ss[0]);
}

// ---------------- K4: per-block partial loss sums ----------------
__global__ __launch_bounds__(256) void loss_partial_kernel(
    const int* __restrict__ pad, const float* __restrict__ denom,
    const float* __restrict__ siji, const float* __restrict__ crossLog,
    float* __restrict__ psum, float* __restrict__ pcnt) {
    int tid = threadIdx.x;
    int idx = blockIdx.x * 256 + tid;
    float term = 0.f, cnt = 0.f;
    if (pad[idx] == 0) {
        float dl = denom[idx], sv = siji[idx], cl = crossLog[idx >> 9];
        float M = fmaxf(sv, cl);
        float neg = M + log1pf(expf(-fabsf(sv - cl)));
        term = 0.5f * (dl + neg) - sv;
        cnt = 1.f;
    }
    __shared__ float bs[256], bc[256];
    bs[tid] = term; bc[tid] = cnt;
    __syncthreads();
    for (int off = 128; off > 0; off >>= 1) {
        if (tid < off) { bs[tid] += bs[tid + off]; bc[tid] += bc[tid + off]; }
        __syncthreads();
    }
    if (tid == 0) { psum[blockIdx.x] = bs[0]; pcnt[blockIdx.x] = bc[0]; }
}

// ---------------- K5: final reduce of 512 partials ----------------
__global__ __launch_bounds__(256) void final_kernel(const float* __restrict__ psum,
                                                    const float* __restrict__ pcnt,
                                                    float* __restrict__ out) {
    int tid = threadIdx.x;
    __shared__ float bs[256], bc[256];
    bs[tid] = psum[tid] + psum[tid + 256];
    bc[tid] = pcnt[tid] + pcnt[tid + 256];
    __syncthreads();
    for (int off = 128; off > 0; off >>= 1) {
        if (tid < off) { bs[tid] += bs[tid + off]; bc[tid] += bc[tid + off]; }
        __syncthreads();
    }
    if (tid == 0) out[0] = bs[0] / bc[0];
}

extern "C" void kernel_launch(void* const* d_in, const int* in_sizes, int n_in,
                              void* d_out, int out_size, void* d_ws, size_t ws_size,
                              hipStream_t stream) {
    (void)in_sizes; (void)n_in; (void)out_size; (void)ws_size;
    const float* text = (const float*)d_in[0];
    const float* img  = (const float*)d_in[1];
    const float* Wml  = (const float*)d_in[2];
    const float* Wmv  = (const float*)d_in[3];
    const float* tau  = (const float*)d_in[4];
    const int* pad    = (const int*)d_in[5];
    float* out = (float*)d_out;

    float* ws = (float*)d_ws;
    float* ip       = ws;                      // 131072 fl
    unsigned short* Cb = (unsigned short*)(ws + 131072);  // 131072 ushort (uses 65536 fl)
    unsigned long long* mbits = (unsigned long long*)(ws + 262144); // 2048 u64
    float* denom    = ws + 266240;             // 131072
    float* siji     = ws + 397312;             // 131072
    float* crossM   = ws + 528384;             // 524288
    float* crossS   = ws + 1052672;            // 524288
    float* crossLog = ws + 1576960;            // 256
    float* psum     = ws + 1577216;            // 512
    float* pcnt     = ws + 1577728;            // 512

    hipLaunchKernelGGL(ip_kernel,   dim3(32),  dim3(256), 0, stream, img, Wmv, ip);
    hipLaunchKernelGGL(c_kernel,    dim3(32),  dim3(256), 0, stream, ip, Wml, tau, Cb);
    hipLaunchKernelGGL(mask_kernel, dim3(L_),  dim3(256), 0, stream, pad, mbits);
    hipLaunchKernelGGL(gemm_mfma_kernel, dim3(NT), dim3(256), 0, stream,
                       text, Cb, mbits, denom, siji, crossM, crossS);
    hipLaunchKernelGGL(cross_combine_kernel, dim3(B_), dim3(256), 0, stream,
                       crossM, crossS, crossLog);
    hipLaunchKernelGGL(loss_partial_kernel, dim3(ROWS / 256), dim3(256), 0, stream,
                       pad, denom, siji, crossLog, psum, pcnt);
    hipLaunchKernelGGL(final_kernel, dim3(1), dim3(256), 0, stream, psum, pcnt, out);
}

// Round 4
// 537.078 us; speedup vs baseline: 1.7074x; 1.7074x over previous
//
#include <hip/hip_runtime.h>
#include <math.h>

// LCGLoss: B=256, L=512, D=512.
// S[(b,l),k] = (text @ C^T)[(b,l),k],  Cb[k][d] = bf16( (ip @ W_ML)[k][d] / tau )
// loss = mean over valid (i,l) of 0.5*(denom_log + logaddexp(s_iji, cross_log[i])) - s_iji

#define B_ 256
#define L_ 512
#define D_ 512
#define ROWS (B_ * L_)      // 131072
#define NT (ROWS / 64)      // 2048 row-tiles
#define NEG_INF (-INFINITY)

typedef __attribute__((ext_vector_type(8))) short s8_t;     // 8 bf16 in 4 VGPRs
typedef __attribute__((ext_vector_type(4))) float f4_t;

__device__ inline unsigned short f2bf(float x) {
    unsigned int u = __float_as_uint(x);
    u += 0x7FFFu + ((u >> 16) & 1u);          // round-to-nearest-even
    return (unsigned short)(u >> 16);
}

// ---------------- K0: ip[k][e] = sum_d img[k][d] * Wmv[e][d]  (64x64 tiles, 32 blocks) ----
__global__ __launch_bounds__(256) void ip_kernel(const float* __restrict__ img,
                                                 const float* __restrict__ Wmv,
                                                 float* __restrict__ ip) {
    int kt = blockIdx.x >> 3, et = blockIdx.x & 7;
    __shared__ float As[64][36];
    __shared__ float Bs[64][36];
    int tid = threadIdx.x;
    int lr = tid >> 2, lc = (tid & 3) * 8;
    int ty = tid >> 4, tx = tid & 15;
    float acc[4][4] = {};
    for (int d0 = 0; d0 < D_; d0 += 32) {
        f4_t a0 = *(const f4_t*)(img + (size_t)(kt * 64 + lr) * D_ + d0 + lc);
        f4_t a1 = *(const f4_t*)(img + (size_t)(kt * 64 + lr) * D_ + d0 + lc + 4);
        f4_t b0 = *(const f4_t*)(Wmv + (size_t)(et * 64 + lr) * D_ + d0 + lc);
        f4_t b1 = *(const f4_t*)(Wmv + (size_t)(et * 64 + lr) * D_ + d0 + lc + 4);
        __syncthreads();
        *(f4_t*)(&As[lr][lc]) = a0; *(f4_t*)(&As[lr][lc + 4]) = a1;
        *(f4_t*)(&Bs[lr][lc]) = b0; *(f4_t*)(&Bs[lr][lc + 4]) = b1;
        __syncthreads();
        for (int d = 0; d < 32; d++) {
            float av[4], bv[4];
#pragma unroll
            for (int i = 0; i < 4; i++) { av[i] = As[ty * 4 + i][d]; bv[i] = Bs[tx * 4 + i][d]; }
#pragma unroll
            for (int i = 0; i < 4; i++)
#pragma unroll
                for (int j = 0; j < 4; j++) acc[i][j] = fmaf(av[i], bv[j], acc[i][j]);
        }
    }
#pragma unroll
    for (int i = 0; i < 4; i++)
#pragma unroll
        for (int j = 0; j < 4; j++)
            ip[(size_t)(kt * 64 + ty * 4 + i) * D_ + et * 64 + tx * 4 + j] = acc[i][j];
}

// ---------------- K1: Cb[k][d] = bf16( sum_e ip[k][e]*Wml[e][d] / tau ) ----------------
__global__ __launch_bounds__(256) void c_kernel(const float* __restrict__ ip,
                                                const float* __restrict__ Wml,
                                                const float* __restrict__ tau,
                                                unsigned short* __restrict__ Cb) {
    int kt = blockIdx.x >> 3, dt = blockIdx.x & 7;
    __shared__ float As[64][36];
    __shared__ float Bs[32][68];
    int tid = threadIdx.x;
    int lr = tid >> 2, lc = (tid & 3) * 8;
    int ber = tid >> 3, bec = (tid & 7) * 8;
    int ty = tid >> 4, tx = tid & 15;
    float acc[4][4] = {};
    for (int e0 = 0; e0 < D_; e0 += 32) {
        f4_t a0 = *(const f4_t*)(ip + (size_t)(kt * 64 + lr) * D_ + e0 + lc);
        f4_t a1 = *(const f4_t*)(ip + (size_t)(kt * 64 + lr) * D_ + e0 + lc + 4);
        f4_t b0 = *(const f4_t*)(Wml + (size_t)(e0 + ber) * D_ + dt * 64 + bec);
        f4_t b1 = *(const f4_t*)(Wml + (size_t)(e0 + ber) * D_ + dt * 64 + bec + 4);
        __syncthreads();
        *(f4_t*)(&As[lr][lc]) = a0; *(f4_t*)(&As[lr][lc + 4]) = a1;
        *(f4_t*)(&Bs[ber][bec]) = b0; *(f4_t*)(&Bs[ber][bec + 4]) = b1;
        __syncthreads();
        for (int e = 0; e < 32; e++) {
            float av[4], bv[4];
#pragma unroll
            for (int i = 0; i < 4; i++) { av[i] = As[ty * 4 + i][e]; bv[i] = Bs[e][tx * 4 + i]; }
#pragma unroll
            for (int i = 0; i < 4; i++)
#pragma unroll
                for (int j = 0; j < 4; j++) acc[i][j] = fmaf(av[i], bv[j], acc[i][j]);
        }
    }
    float it = 1.0f / fmaxf(tau[0], 0.001f);
#pragma unroll
    for (int i = 0; i < 4; i++)
#pragma unroll
        for (int j = 0; j < 4; j++)
            Cb[(size_t)(kt * 64 + ty * 4 + i) * D_ + dt * 64 + tx * 4 + j] = f2bf(acc[i][j] * it);
}

// ---------------- Kmask: mbits[l*4+w] bit j = valid[w*64+j, l] ----------------
__global__ __launch_bounds__(256) void mask_kernel(const int* __restrict__ pad,
                                                   unsigned long long* __restrict__ mbits) {
    int l = blockIdx.x;
    int w = threadIdx.x >> 6;
    int j = threadIdx.x & 63;
    unsigned long long bal = __ballot(pad[(w * 64 + j) * L_ + l] == 0);
    if (j == 0) mbits[l * 4 + w] = bal;
}

// ---------------- K2: bf16 MFMA GEMM (64 rows x 256 cols per block) + fused reductions ----
__global__ __launch_bounds__(256) void gemm_mfma_kernel(
    const float* __restrict__ text, const unsigned short* __restrict__ Cb,
    const unsigned long long* __restrict__ mbits,
    float* __restrict__ denom, float* __restrict__ siji,
    float* __restrict__ crossM, float* __restrict__ crossS) {
    // staging (phase 1): a_s 64x40 bf16 (1280 fl), b_s 256x40 bf16 (5120 fl)
    // epilogue (phase 2): Sh[32][257] + pm/ps[128] + rvf[32] = 8512 fl (34 KB)
    __shared__ __align__(16) float lds[8512];
    unsigned short* a_s = (unsigned short*)lds;
    unsigned short* b_s = (unsigned short*)(lds + 1280);
    float* Sh  = lds;
    float* pm  = lds + 8224;
    float* ps  = lds + 8352;
    float* rvf = lds + 8480;

    const int tile = blockIdx.x;
    const int row0 = tile * 64;
    const int bIdx = row0 >> 9;
    const int l0 = row0 & 511;
    const int tid = threadIdx.x;
    const int wave = tid >> 6;
    const int lane = tid & 63;
    const int qd = lane >> 4;     // quad 0..3
    const int mm = lane & 15;

    f4_t acc[4][4];
#pragma unroll
    for (int mt = 0; mt < 4; mt++)
#pragma unroll
        for (int nt = 0; nt < 4; nt++)
#pragma unroll
            for (int r = 0; r < 4; r++) acc[mt][nt][r] = 0.f;

    const int arow = tid >> 2, akq = tid & 3;
    const float* aptr = text + (size_t)(row0 + arow) * D_ + akq * 8;
    const int bkq = tid & 3, bn = tid >> 2;
    const unsigned short* bptr = Cb + (size_t)bn * D_ + bkq * 8;

#pragma unroll 1
    for (int k0 = 0; k0 < D_; k0 += 32) {
        f4_t av0 = *(const f4_t*)(aptr + k0);
        f4_t av1 = *(const f4_t*)(aptr + k0 + 4);
        s8_t bv[4];
#pragma unroll
        for (int i = 0; i < 4; i++)
            bv[i] = *(const s8_t*)(bptr + (size_t)i * 64 * D_ + k0);
        __syncthreads();
        s8_t a8;
        a8[0] = (short)f2bf(av0[0]); a8[1] = (short)f2bf(av0[1]);
        a8[2] = (short)f2bf(av0[2]); a8[3] = (short)f2bf(av0[3]);
        a8[4] = (short)f2bf(av1[0]); a8[5] = (short)f2bf(av1[1]);
        a8[6] = (short)f2bf(av1[2]); a8[7] = (short)f2bf(av1[3]);
        *(s8_t*)(a_s + arow * 40 + akq * 8) = a8;
#pragma unroll
        for (int i = 0; i < 4; i++)
            *(s8_t*)(b_s + (bn + i * 64) * 40 + bkq * 8) = bv[i];
        __syncthreads();
        s8_t af[4], bf[4];
#pragma unroll
        for (int mt = 0; mt < 4; mt++)
            af[mt] = *(const s8_t*)(a_s + (mt * 16 + mm) * 40 + qd * 8);
#pragma unroll
        for (int nt = 0; nt < 4; nt++)
            bf[nt] = *(const s8_t*)(b_s + (wave * 64 + nt * 16 + mm) * 40 + qd * 8);
#pragma unroll
        for (int mt = 0; mt < 4; mt++)
#pragma unroll
            for (int nt = 0; nt < 4; nt++)
                acc[mt][nt] = __builtin_amdgcn_mfma_f32_16x16x32_bf16(
                    af[mt], bf[nt], acc[mt][nt], 0, 0, 0);
    }

    // -------- epilogue: two 32-row halves through LDS --------
    // NOTE: h-loop MUST be fully unrolled — acc[h*2+mt2] with runtime h makes the
    // index dynamic, blocks SROA, and spills the whole accumulator array to
    // scratch for the entire kernel (R3: 2.07 GB WRITE_SIZE, 16x slowdown).
    float cm = NEG_INF, cs = 0.f;
    const int mw = bIdx >> 6, mb = bIdx & 63;

#pragma unroll
    for (int h = 0; h < 2; h++) {
        __syncthreads();                 // staging/frag reads (h=0) or prev-half reads done
        // write MFMA C-layout frags: row = mt*16 + qd*4 + r, col = wave*64 + nt*16 + mm
#pragma unroll
        for (int mt2 = 0; mt2 < 2; mt2++) {
            int mt = h * 2 + mt2;
            int rl = mt2 * 16 + qd * 4;  // row within this 32-row half
#pragma unroll
            for (int nt = 0; nt < 4; nt++) {
                int col = wave * 64 + nt * 16 + mm;
#pragma unroll
                for (int r = 0; r < 4; r++)
                    Sh[(rl + r) * 257 + col] = acc[mt][nt][r];
            }
        }
        if (tid < 32) {
            int l = l0 + h * 32 + tid;
            rvf[tid] = (float)((mbits[l * 4 + mw] >> mb) & 1ULL);  // valid[bIdx, l]
        }
        __syncthreads();

        // cross partial: column = tid, exclude column == bIdx; rows need valid[bIdx,l]
        if (tid != bIdx) {
            float m2 = NEG_INF;
            for (int r = 0; r < 32; r++)
                if (rvf[r] != 0.f) m2 = fmaxf(m2, Sh[r * 257 + tid]);
            if (m2 > NEG_INF) {
                float s2 = 0.f;
                for (int r = 0; r < 32; r++)
                    if (rvf[r] != 0.f) s2 += expf(Sh[r * 257 + tid] - m2);
                if (cm == NEG_INF) { cm = m2; cs = s2; }
                else {
                    float M = fmaxf(cm, m2);
                    cs = cs * expf(cm - M) + s2 * expf(m2 - M);
                    cm = M;
                }
            }
        }
        // denom partials: 128 threads, (row = tid&31, grp = tid>>5 covering 64 cols)
        if (tid < 128) {
            int row = tid & 31, grp = tid >> 5;
            int l = l0 + h * 32 + row;
            unsigned long long bits = mbits[l * 4 + grp];
            const float* Srow = Sh + row * 257 + grp * 64;
            float m = NEG_INF;
            for (int c = 0; c < 64; c++)
                if ((bits >> c) & 1ULL) m = fmaxf(m, Srow[c]);
            float s = 0.f;
            if (m > NEG_INF)
                for (int c = 0; c < 64; c++)
                    if ((bits >> c) & 1ULL) s += expf(Srow[c] - m);
            pm[grp * 32 + row] = m;
            ps[grp * 32 + row] = s;
        }
        __syncthreads();
        if (tid < 32) {
            float m0 = pm[tid], m1 = pm[32 + tid], m2 = pm[64 + tid], m3 = pm[96 + tid];
            float M = fmaxf(fmaxf(m0, m1), fmaxf(m2, m3));
            float dl;
            if (M == NEG_INF) dl = NEG_INF;
            else {
                float s = ps[tid] * expf(m0 - M) + ps[32 + tid] * expf(m1 - M) +
                          ps[64 + tid] * expf(m2 - M) + ps[96 + tid] * expf(m3 - M);
                dl = M + logf(s);
            }
            int gr = row0 + h * 32 + tid;
            denom[gr] = dl;
            siji[gr] = Sh[tid * 257 + bIdx];
        }
    }
    crossM[(size_t)tid * NT + tile] = cm;
    crossS[(size_t)tid * NT + tile] = cs;
}

// ---------------- K3: cross_log[i] = merge of 2048 (m,s) partials ----------------
__global__ __launch_bounds__(256) void cross_combine_kernel(const float* __restrict__ crossM,
                                                            const float* __restrict__ crossS,
                                                            float* __restrict__ crossLog) {
    int i = blockIdx.x;
    int tid = threadIdx.x;
    float m = NEG_INF, s = 0.f;
    for (int e = 0; e < NT / 256; e++) {
        int t = e * 256 + tid;
        float m2 = crossM[(size_t)i * NT + t];
        float s2 = crossS[(size_t)i * NT + t];
        if (m2 > NEG_INF) {
            if (m == NEG_INF) { m = m2; s = s2; }
            else {
                float M = fmaxf(m, m2);
                s = s * expf(m - M) + s2 * expf(m2 - M);
                m = M;
            }
        }
    }
    __shared__ float sm[256], ss[256];
    sm[tid] = m; ss[tid] = s;
    __syncthreads();
    for (int off = 128; off > 0; off >>= 1) {
        if (tid < off) {
            float m1 = sm[tid], s1 = ss[tid];
            float m2 = sm[tid + off], s2 = ss[tid + off];
            float M = fmaxf(m1, m2);
            float sv;
            if (M == NEG_INF) sv = 0.f;
            else sv = s1 * expf(m1 - M) + s2 * expf(m2 - M);
            sm[tid] = M; ss[tid] = sv;
        }
        __syncthreads();
    }
    if (tid == 0) crossLog[i] = (sm[0] == NEG_INF) ? NEG_INF : sm[0] + logf(ss[0]);
}

// ---------------- K4: per-block partial loss sums ----------------
__global__ __launch_bounds__(256) void loss_partial_kernel(
    const int* __restrict__ pad, const float* __restrict__ denom,
    const float* __restrict__ siji, const float* __restrict__ crossLog,
    float* __restrict__ psum, float* __restrict__ pcnt) {
    int tid = threadIdx.x;
    int idx = blockIdx.x * 256 + tid;
    float term = 0.f, cnt = 0.f;
    if (pad[idx] == 0) {
        float dl = denom[idx], sv = siji[idx], cl = crossLog[idx >> 9];
        float M = fmaxf(sv, cl);
        float neg = M + log1pf(expf(-fabsf(sv - cl)));
        term = 0.5f * (dl + neg) - sv;
        cnt = 1.f;
    }
    __shared__ float bs[256], bc[256];
    bs[tid] = term; bc[tid] = cnt;
    __syncthreads();
    for (int off = 128; off > 0; off >>= 1) {
        if (tid < off) { bs[tid] += bs[tid + off]; bc[tid] += bc[tid + off]; }
        __syncthreads();
    }
    if (tid == 0) { psum[blockIdx.x] = bs[0]; pcnt[blockIdx.x] = bc[0]; }
}

// ---------------- K5: final reduce of 512 partials ----------------
__global__ __launch_bounds__(256) void final_kernel(const float* __restrict__ psum,
                                                    const float* __restrict__ pcnt,
                                                    float* __restrict__ out) {
    int tid = threadIdx.x;
    __shared__ float bs[256], bc[256];
    bs[tid] = psum[tid] + psum[tid + 256];
    bc[tid] = pcnt[tid] + pcnt[tid + 256];
    __syncthreads();
    for (int off = 128; off > 0; off >>= 1) {
        if (tid < off) { bs[tid] += bs[tid + off]; bc[tid] += bc[tid + off]; }
        __syncthreads();
    }
    if (tid == 0) out[0] = bs[0] / bc[0];
}

extern "C" void kernel_launch(void* const* d_in, const int* in_sizes, int n_in,
                              void* d_out, int out_size, void* d_ws, size_t ws_size,
                              hipStream_t stream) {
    (void)in_sizes; (void)n_in; (void)out_size; (void)ws_size;
    const float* text = (const float*)d_in[0];
    const float* img  = (const float*)d_in[1];
    const float* Wml  = (const float*)d_in[2];
    const float* Wmv  = (const float*)d_in[3];
    const float* tau  = (const float*)d_in[4];
    const int* pad    = (const int*)d_in[5];
    float* out = (float*)d_out;

    float* ws = (float*)d_ws;
    float* ip       = ws;                      // 131072 fl
    unsigned short* Cb = (unsigned short*)(ws + 131072);  // 131072 ushort
    unsigned long long* mbits = (unsigned long long*)(ws + 262144); // 2048 u64
    float* denom    = ws + 266240;             // 131072
    float* siji     = ws + 397312;             // 131072
    float* crossM   = ws + 528384;             // 524288
    float* crossS   = ws + 1052672;            // 524288
    float* crossLog = ws + 1576960;            // 256
    float* psum     = ws + 1577216;            // 512
    float* pcnt     = ws + 1577728;            // 512

    hipLaunchKernelGGL(ip_kernel,   dim3(32),  dim3(256), 0, stream, img, Wmv, ip);
    hipLaunchKernelGGL(c_kernel,    dim3(32),  dim3(256), 0, stream, ip, Wml, tau, Cb);
    hipLaunchKernelGGL(mask_kernel, dim3(L_),  dim3(256), 0, stream, pad, mbits);
    hipLaunchKernelGGL(gemm_mfma_kernel, dim3(NT), dim3(256), 0, stream,
                       text, Cb, mbits, denom, siji, crossM, crossS);
    hipLaunchKernelGGL(cross_combine_kernel, dim3(B_), dim3(256), 0, stream,
                       crossM, crossS, crossLog);
    hipLaunchKernelGGL(loss_partial_kernel, dim3(ROWS / 256), dim3(256), 0, stream,
                       pad, denom, siji, crossLog, psum, pcnt);
    hipLaunchKernelGGL(final_kernel, dim3(1), dim3(256), 0, stream, psum, pcnt, out);
}

// Round 5
// 495.094 us; speedup vs baseline: 1.8521x; 1.0848x over previous
//
#include <hip/hip_runtime.h>
#include <math.h>

// LCGLoss: B=256, L=512, D=512.
// S[(b,l),k] = (text @ C^T)[(b,l),k],  Cb[k][d] = bf16( (ip @ W_ML)[k][d] / tau )
// loss = mean over valid (i,l) of 0.5*(denom_log + logaddexp(s_iji, cross_log[i])) - s_iji

#define B_ 256
#define L_ 512
#define D_ 512
#define ROWS (B_ * L_)      // 131072
#define NT (ROWS / 64)      // 2048 row-tiles
#define NEG_INF (-INFINITY)

typedef __attribute__((ext_vector_type(8))) short s8_t;     // 8 bf16 in 4 VGPRs
typedef __attribute__((ext_vector_type(4))) float f4_t;
typedef __attribute__((ext_vector_type(2))) float f2_t;
typedef __attribute__((ext_vector_type(4))) unsigned short us4_t;

__device__ inline unsigned short f2bf(float x) {
    unsigned int u = __float_as_uint(x);
    u += 0x7FFFu + ((u >> 16) & 1u);          // round-to-nearest-even
    return (unsigned short)(u >> 16);
}

// ---------------- K0: ip[k][e] = sum_d img[k][d]*Wmv[e][d]; 32k x 64e tiles, 64 blocks ----
__global__ __launch_bounds__(256) void ip_kernel(const float* __restrict__ img,
                                                 const float* __restrict__ Wmv,
                                                 float* __restrict__ ip) {
    int kt = blockIdx.x >> 3, et = blockIdx.x & 7;
    __shared__ float Ast[32][36];   // [d][krow]  (transposed)
    __shared__ float Bst[32][72];   // [d][ecol]  (transposed, 16B-aligned rows)
    int tid = threadIdx.x;
    int ty = tid >> 4;              // 0..15 -> rows ty*2
    int tx = tid & 15;              // cols tx*4
    float acc[2][4] = {};
    int sr = tid >> 3, sc = (tid & 7) * 4;
    for (int d0 = 0; d0 < D_; d0 += 32) {
        f4_t a = *(const f4_t*)(img + (size_t)(kt * 32 + sr) * D_ + d0 + sc);
        f4_t b0 = *(const f4_t*)(Wmv + (size_t)(et * 64 + sr) * D_ + d0 + sc);
        f4_t b1 = *(const f4_t*)(Wmv + (size_t)(et * 64 + sr + 32) * D_ + d0 + sc);
        __syncthreads();
#pragma unroll
        for (int m = 0; m < 4; m++) {
            Ast[sc + m][sr] = a[m];
            Bst[sc + m][sr] = b0[m];
            Bst[sc + m][sr + 32] = b1[m];
        }
        __syncthreads();
#pragma unroll 4
        for (int d = 0; d < 32; d++) {
            f2_t a2 = *(const f2_t*)&Ast[d][ty * 2];
            f4_t b4 = *(const f4_t*)&Bst[d][tx * 4];
#pragma unroll
            for (int i = 0; i < 2; i++)
#pragma unroll
                for (int j = 0; j < 4; j++) acc[i][j] = fmaf(a2[i], b4[j], acc[i][j]);
        }
    }
#pragma unroll
    for (int i = 0; i < 2; i++) {
        f4_t o; o[0] = acc[i][0]; o[1] = acc[i][1]; o[2] = acc[i][2]; o[3] = acc[i][3];
        *(f4_t*)(ip + (size_t)(kt * 32 + ty * 2 + i) * D_ + et * 64 + tx * 4) = o;
    }
}

// ---------------- K1: Cb[k][d] = bf16( sum_e ip[k][e]*Wml[e][d] / tau ); 64 blocks -------
__global__ __launch_bounds__(256) void c_kernel(const float* __restrict__ ip,
                                                const float* __restrict__ Wml,
                                                const float* __restrict__ tau,
                                                unsigned short* __restrict__ Cb) {
    int kt = blockIdx.x >> 3, dt = blockIdx.x & 7;
    __shared__ float Ast[32][36];   // [e][krow] (transposed)
    __shared__ float Bst[32][72];   // [e][dcol] (direct rows of Wml)
    int tid = threadIdx.x;
    int ty = tid >> 4;
    int tx = tid & 15;
    float acc[2][4] = {};
    int sr = tid >> 3, sc = (tid & 7) * 4;       // A staging
    int br = tid >> 4, bc = (tid & 15) * 4;      // B staging (16 rows x 64 cols per pass)
    for (int e0 = 0; e0 < D_; e0 += 32) {
        f4_t a = *(const f4_t*)(ip + (size_t)(kt * 32 + sr) * D_ + e0 + sc);
        f4_t b0 = *(const f4_t*)(Wml + (size_t)(e0 + br) * D_ + dt * 64 + bc);
        f4_t b1 = *(const f4_t*)(Wml + (size_t)(e0 + br + 16) * D_ + dt * 64 + bc);
        __syncthreads();
#pragma unroll
        for (int m = 0; m < 4; m++) Ast[sc + m][sr] = a[m];
        *(f4_t*)&Bst[br][bc] = b0;
        *(f4_t*)&Bst[br + 16][bc] = b1;
        __syncthreads();
#pragma unroll 4
        for (int e = 0; e < 32; e++) {
            f2_t a2 = *(const f2_t*)&Ast[e][ty * 2];
            f4_t b4 = *(const f4_t*)&Bst[e][tx * 4];
#pragma unroll
            for (int i = 0; i < 2; i++)
#pragma unroll
                for (int j = 0; j < 4; j++) acc[i][j] = fmaf(a2[i], b4[j], acc[i][j]);
        }
    }
    float it = 1.0f / fmaxf(tau[0], 0.001f);
#pragma unroll
    for (int i = 0; i < 2; i++) {
        us4_t o;
#pragma unroll
        for (int j = 0; j < 4; j++) o[j] = f2bf(acc[i][j] * it);
        *(us4_t*)(Cb + (size_t)(kt * 32 + ty * 2 + i) * D_ + dt * 64 + tx * 4) = o;
    }
}

// ---------------- Kmask: mbits[l*4+w] bit j = valid[w*64+j, l] ----------------
__global__ __launch_bounds__(256) void mask_kernel(const int* __restrict__ pad,
                                                   unsigned long long* __restrict__ mbits) {
    int l = blockIdx.x;
    int w = threadIdx.x >> 6;
    int j = threadIdx.x & 63;
    unsigned long long bal = __ballot(pad[(w * 64 + j) * L_ + l] == 0);
    if (j == 0) mbits[l * 4 + w] = bal;
}

// ======== gemm helpers (always_inline so acc stays in registers) ========
struct StageRegs { f4_t av0, av1; s8_t bv0, bv1, bv2, bv3; };

__device__ __attribute__((always_inline)) inline void g_load(
    const float* aptr, const unsigned short* bptr, int koff, StageRegs& r) {
    r.av0 = *(const f4_t*)(aptr + koff);
    r.av1 = *(const f4_t*)(aptr + koff + 4);
    r.bv0 = *(const s8_t*)(bptr + koff);
    r.bv1 = *(const s8_t*)(bptr + (size_t)64 * D_ + koff);
    r.bv2 = *(const s8_t*)(bptr + (size_t)128 * D_ + koff);
    r.bv3 = *(const s8_t*)(bptr + (size_t)192 * D_ + koff);
}

__device__ __attribute__((always_inline)) inline void lds_store(
    unsigned short* a_s, unsigned short* b_s, int arow, int akq, int bn, int bkq,
    const StageRegs& r) {
    s8_t a8;
    a8[0] = (short)f2bf(r.av0[0]); a8[1] = (short)f2bf(r.av0[1]);
    a8[2] = (short)f2bf(r.av0[2]); a8[3] = (short)f2bf(r.av0[3]);
    a8[4] = (short)f2bf(r.av1[0]); a8[5] = (short)f2bf(r.av1[1]);
    a8[6] = (short)f2bf(r.av1[2]); a8[7] = (short)f2bf(r.av1[3]);
    *(s8_t*)(a_s + arow * 40 + akq * 8) = a8;
    *(s8_t*)(b_s + (bn + 0) * 40 + bkq * 8)   = r.bv0;
    *(s8_t*)(b_s + (bn + 64) * 40 + bkq * 8)  = r.bv1;
    *(s8_t*)(b_s + (bn + 128) * 40 + bkq * 8) = r.bv2;
    *(s8_t*)(b_s + (bn + 192) * 40 + bkq * 8) = r.bv3;
}

__device__ __attribute__((always_inline)) inline void do_mfma(
    const unsigned short* a_s, const unsigned short* b_s, int mm, int qd, int wave,
    f4_t acc[4][4]) {
    s8_t af[4], bf[4];
#pragma unroll
    for (int mt = 0; mt < 4; mt++)
        af[mt] = *(const s8_t*)(a_s + (mt * 16 + mm) * 40 + qd * 8);
#pragma unroll
    for (int nt = 0; nt < 4; nt++)
        bf[nt] = *(const s8_t*)(b_s + (wave * 64 + nt * 16 + mm) * 40 + qd * 8);
#pragma unroll
    for (int mt = 0; mt < 4; mt++)
#pragma unroll
        for (int nt = 0; nt < 4; nt++)
            acc[mt][nt] = __builtin_amdgcn_mfma_f32_16x16x32_bf16(
                af[mt], bf[nt], acc[mt][nt], 0, 0, 0);
}

// ---------------- K2: bf16 MFMA GEMM (64x256 per block), double-buffered, fused epilogue --
__global__ __launch_bounds__(256) void gemm_mfma_kernel(
    const float* __restrict__ text, const unsigned short* __restrict__ Cb,
    const unsigned long long* __restrict__ mbits,
    float* __restrict__ denom, float* __restrict__ siji,
    float* __restrict__ crossM, float* __restrict__ crossS) {
    // buffers: 2 x (A 64x40 + B 256x40) bf16 = 2 x 12800 halves = 51200 B
    // epilogue overlay: Sh[32][257] + pm/ps[128] + rvadj[32] = 8512 floats
    __shared__ __align__(16) float lds[12800];
    unsigned short* A0 = (unsigned short*)lds;
    unsigned short* Bb0 = A0 + 2560;
    unsigned short* A1 = A0 + 12800;
    unsigned short* Bb1 = A1 + 2560;
    float* Sh  = lds;
    float* pm  = lds + 8224;
    float* ps  = lds + 8352;
    float* rvadj = lds + 8480;

    const int tile = blockIdx.x;
    const int row0 = tile * 64;
    const int bIdx = row0 >> 9;
    const int l0 = row0 & 511;
    const int tid = threadIdx.x;
    const int wave = tid >> 6;
    const int lane = tid & 63;
    const int qd = lane >> 4;
    const int mm = lane & 15;

    f4_t acc[4][4];
#pragma unroll
    for (int mt = 0; mt < 4; mt++)
#pragma unroll
        for (int nt = 0; nt < 4; nt++)
#pragma unroll
            for (int r = 0; r < 4; r++) acc[mt][nt][r] = 0.f;

    const int arow = tid >> 2, akq = tid & 3;
    const float* aptr = text + (size_t)(row0 + arow) * D_ + akq * 8;
    const int bkq = tid & 3, bn = tid >> 2;
    const unsigned short* bptr = Cb + (size_t)bn * D_ + bkq * 8;

    StageRegs rg;
    g_load(aptr, bptr, 0, rg);
    lds_store(A0, Bb0, arow, akq, bn, bkq, rg);
#pragma unroll 1
    for (int k0 = 0; k0 < 16; k0 += 2) {
        g_load(aptr, bptr, (k0 + 1) * 32, rg);       // prefetch k0+1 (always valid, k0<=14)
        __syncthreads();
        do_mfma(A0, Bb0, mm, qd, wave, acc);         // compute k0
        lds_store(A1, Bb1, arow, akq, bn, bkq, rg);  // publish k0+1
        bool more = (k0 + 2) < 16;
        if (more) g_load(aptr, bptr, (k0 + 2) * 32, rg);
        __syncthreads();
        do_mfma(A1, Bb1, mm, qd, wave, acc);         // compute k0+1
        if (more) lds_store(A0, Bb0, arow, akq, bn, bkq, rg);
    }

    // -------- epilogue: two 32-row halves through LDS; branch-free masked reductions -----
    // NOTE: h-loop MUST stay fully unrolled — runtime acc index spills the whole
    // accumulator to scratch (R3: 2.07 GB WRITE_SIZE, 16x slowdown).
    float cm = NEG_INF, cs = 0.f;
    const int mw = bIdx >> 6, mb = bIdx & 63;

#pragma unroll
    for (int h = 0; h < 2; h++) {
        __syncthreads();
#pragma unroll
        for (int mt2 = 0; mt2 < 2; mt2++) {
            int mt = h * 2 + mt2;
            int rl = mt2 * 16 + qd * 4;
#pragma unroll
            for (int nt = 0; nt < 4; nt++) {
                int col = wave * 64 + nt * 16 + mm;
#pragma unroll
                for (int r = 0; r < 4; r++)
                    Sh[(rl + r) * 257 + col] = acc[mt][nt][r];
            }
        }
        if (tid < 32) {
            int l = l0 + h * 32 + tid;
            rvadj[tid] = ((mbits[l * 4 + mw] >> mb) & 1ULL) ? 0.f : NEG_INF;
        }
        __syncthreads();

        // cross partial for column tid (exclusion of col==bIdx applied at the end)
        {
            float m2 = NEG_INF;
#pragma unroll 8
            for (int r = 0; r < 32; r++)
                m2 = fmaxf(m2, Sh[r * 257 + tid] + rvadj[r]);
            if (m2 > NEG_INF) {
                float s2 = 0.f;
#pragma unroll 8
                for (int r = 0; r < 32; r++)
                    s2 += __expf(Sh[r * 257 + tid] + rvadj[r] - m2);
                float M = fmaxf(cm, m2);
                cs = cs * __expf(cm - M) + s2 * __expf(m2 - M);
                cm = M;
            }
        }
        // denom partials: 128 threads, (row = tid&31, grp = tid>>5 covering 64 cols)
        if (tid < 128) {
            int row = tid & 31, grp = tid >> 5;
            int l = l0 + h * 32 + row;
            unsigned long long bits = mbits[l * 4 + grp];
            const float* Srow = Sh + row * 257 + grp * 64;
            float m = NEG_INF;
#pragma unroll 8
            for (int c = 0; c < 64; c++) {
                float adj = ((bits >> c) & 1ULL) ? 0.f : NEG_INF;
                m = fmaxf(m, Srow[c] + adj);
            }
            float s = 0.f;
            if (m > NEG_INF) {
#pragma unroll 8
                for (int c = 0; c < 64; c++) {
                    float adj = ((bits >> c) & 1ULL) ? 0.f : NEG_INF;
                    s += __expf(Srow[c] + adj - m);
                }
            }
            pm[grp * 32 + row] = m;
            ps[grp * 32 + row] = s;
        }
        __syncthreads();
        if (tid < 32) {
            float m0 = pm[tid], m1 = pm[32 + tid], m2 = pm[64 + tid], m3 = pm[96 + tid];
            float M = fmaxf(fmaxf(m0, m1), fmaxf(m2, m3));
            float dl;
            if (M == NEG_INF) dl = NEG_INF;
            else {
                float s = ps[tid] * __expf(m0 - M) + ps[32 + tid] * __expf(m1 - M) +
                          ps[64 + tid] * __expf(m2 - M) + ps[96 + tid] * __expf(m3 - M);
                dl = M + __logf(s);
            }
            int gr = row0 + h * 32 + tid;
            denom[gr] = dl;
            siji[gr] = Sh[tid * 257 + bIdx];
        }
    }
    if (tid == bIdx) { cm = NEG_INF; cs = 0.f; }    // k == i exclusion
    crossM[(size_t)tid * NT + tile] = cm;
    crossS[(size_t)tid * NT + tile] = cs;
}

// ---------------- K3: cross_log[i] = merge of 2048 (m,s) partials ----------------
__global__ __launch_bounds__(256) void cross_combine_kernel(const float* __restrict__ crossM,
                                                            const float* __restrict__ crossS,
                                                            float* __restrict__ crossLog) {
    int i = blockIdx.x;
    int tid = threadIdx.x;
    float m = NEG_INF, s = 0.f;
    for (int e = 0; e < NT / 256; e++) {
        int t = e * 256 + tid;
        float m2 = crossM[(size_t)i * NT + t];
        float s2 = crossS[(size_t)i * NT + t];
        if (m2 > NEG_INF) {
            if (m == NEG_INF) { m = m2; s = s2; }
            else {
                float M = fmaxf(m, m2);
                s = s * expf(m - M) + s2 * expf(m2 - M);
                m = M;
            }
        }
    }
    __shared__ float sm[256], ss[256];
    sm[tid] = m; ss[tid] = s;
    __syncthreads();
    for (int off = 128; off > 0; off >>= 1) {
        if (tid < off) {
            float m1 = sm[tid], s1 = ss[tid];
            float m2 = sm[tid + off], s2 = ss[tid + off];
            float M = fmaxf(m1, m2);
            float sv;
            if (M == NEG_INF) sv = 0.f;
            else sv = s1 * expf(m1 - M) + s2 * expf(m2 - M);
            sm[tid] = M; ss[tid] = sv;
        }
        __syncthreads();
    }
    if (tid == 0) crossLog[i] = (sm[0] == NEG_INF) ? NEG_INF : sm[0] + logf(ss[0]);
}

// ---------------- K4: per-block partial loss sums ----------------
__global__ __launch_bounds__(256) void loss_partial_kernel(
    const int* __restrict__ pad, const float* __restrict__ denom,
    const float* __restrict__ siji, const float* __restrict__ crossLog,
    float* __restrict__ psum, float* __restrict__ pcnt) {
    int tid = threadIdx.x;
    int idx = blockIdx.x * 256 + tid;
    float term = 0.f, cnt = 0.f;
    if (pad[idx] == 0) {
        float dl = denom[idx], sv = siji[idx], cl = crossLog[idx >> 9];
        float M = fmaxf(sv, cl);
        float neg = M + log1pf(expf(-fabsf(sv - cl)));
        term = 0.5f * (dl + neg) - sv;
        cnt = 1.f;
    }
    __shared__ float bs[256], bc[256];
    bs[tid] = term; bc[tid] = cnt;
    __syncthreads();
    for (int off = 128; off > 0; off >>= 1) {
        if (tid < off) { bs[tid] += bs[tid + off]; bc[tid] += bc[tid + off]; }
        __syncthreads();
    }
    if (tid == 0) { psum[blockIdx.x] = bs[0]; pcnt[blockIdx.x] = bc[0]; }
}

// ---------------- K5: final reduce of 512 partials ----------------
__global__ __launch_bounds__(256) void final_kernel(const float* __restrict__ psum,
                                                    const float* __restrict__ pcnt,
                                                    float* __restrict__ out) {
    int tid = threadIdx.x;
    __shared__ float bs[256], bc[256];
    bs[tid] = psum[tid] + psum[tid + 256];
    bc[tid] = pcnt[tid] + pcnt[tid + 256];
    __syncthreads();
    for (int off = 128; off > 0; off >>= 1) {
        if (tid < off) { bs[tid] += bs[tid + off]; bc[tid] += bc[tid + off]; }
        __syncthreads();
    }
    if (tid == 0) out[0] = bs[0] / bc[0];
}

extern "C" void kernel_launch(void* const* d_in, const int* in_sizes, int n_in,
                              void* d_out, int out_size, void* d_ws, size_t ws_size,
                              hipStream_t stream) {
    (void)in_sizes; (void)n_in; (void)out_size; (void)ws_size;
    const float* text = (const float*)d_in[0];
    const float* img  = (const float*)d_in[1];
    const float* Wml  = (const float*)d_in[2];
    const float* Wmv  = (const float*)d_in[3];
    const float* tau  = (const float*)d_in[4];
    const int* pad    = (const int*)d_in[5];
    float* out = (float*)d_out;

    float* ws = (float*)d_ws;
    float* ip       = ws;                      // 131072 fl
    unsigned short* Cb = (unsigned short*)(ws + 131072);  // 131072 ushort
    unsigned long long* mbits = (unsigned long long*)(ws + 262144); // 2048 u64
    float* denom    = ws + 266240;             // 131072
    float* siji     = ws + 397312;             // 131072
    float* crossM   = ws + 528384;             // 524288
    float* crossS   = ws + 1052672;            // 524288
    float* crossLog = ws + 1576960;            // 256
    float* psum     = ws + 1577216;            // 512
    float* pcnt     = ws + 1577728;            // 512

    hipLaunchKernelGGL(ip_kernel,   dim3(64),  dim3(256), 0, stream, img, Wmv, ip);
    hipLaunchKernelGGL(c_kernel,    dim3(64),  dim3(256), 0, stream, ip, Wml, tau, Cb);
    hipLaunchKernelGGL(mask_kernel, dim3(L_),  dim3(256), 0, stream, pad, mbits);
    hipLaunchKernelGGL(gemm_mfma_kernel, dim3(NT), dim3(256), 0, stream,
                       text, Cb, mbits, denom, siji, crossM, crossS);
    hipLaunchKernelGGL(cross_combine_kernel, dim3(B_), dim3(256), 0, stream,
                       crossM, crossS, crossLog);
    hipLaunchKernelGGL(loss_partial_kernel, dim3(ROWS / 256), dim3(256), 0, stream,
                       pad, denom, siji, crossLog, psum, pcnt);
    hipLaunchKernelGGL(final_kernel, dim3(1), dim3(256), 0, stream, psum, pcnt, out);
}